// Round 3
// baseline (162.820 us; speedup 1.0000x reference)
//
#include <hip/hip_runtime.h>
#include <hip/hip_bf16.h>

// Causal linear attention, chunked. B=4 H=16 T=2048 D=64. C=256, NC=8, BH=64.
// Kernel 1 (state):  KV_c = K_c^T V_c (64x64 fp32) -> ws, chunks 0..6 only.
// Kernel 2 (attn):   O = Q_c @ prefixKV + tril(Q_c K_c^T) @ V_c.
// bf16 MFMA 16x16x32, fp32 accum. Two regular launches (cooperative launch
// silently fails under this harness's graph capture -- round-2 evidence).

#define T_   2048
#define D_   64
#define CCH  256
#define NCH  8
#define LW   72   // bf16 row stride: 144 B, 16B-aligned; reads ~2-way = free

typedef __bf16 bf16x8 __attribute__((ext_vector_type(8)));
typedef float  f32x4  __attribute__((ext_vector_type(4)));

// MFMA 16x16x32 bf16 fragment layouts (HW-verified, round-1 passing):
//   A: A[m = lane&15][k = (lane>>4)*8 + j]
//   B: B[k = (lane>>4)*8 + j][n = lane&15]
//   C/D: row = (lane>>4)*4 + reg, col = lane&15

__device__ inline bf16x8 pack8(float4 a, float4 b) {
  bf16x8 r;
  r[0] = (__bf16)a.x; r[1] = (__bf16)a.y; r[2] = (__bf16)a.z; r[3] = (__bf16)a.w;
  r[4] = (__bf16)b.x; r[5] = (__bf16)b.y; r[6] = (__bf16)b.z; r[7] = (__bf16)b.w;
  return r;
}

// ------------------------- kernel 1: chunk states -------------------------
__global__ __launch_bounds__(256, 2) void state_kernel(
    const float* __restrict__ k, const float* __restrict__ v,
    float* __restrict__ kvws) {
  __shared__ __align__(16) __bf16 KT[64][LW];  // [d][s]
  __shared__ __align__(16) __bf16 VT[64][LW];  // [d][s]

  const int tid  = threadIdx.x;
  const int lane = tid & 63;
  const int w    = tid >> 6;
  const int quad = lane >> 4;
  const int l15  = lane & 15;
  const int bh   = blockIdx.x >> 3;
  const int c    = blockIdx.x & (NCH - 1);
  if (c == NCH - 1) return;  // last chunk's state never consumed
  const long base = ((long)bh * T_ + (long)c * CCH) * D_;
  const int d0   = w * 16;

  const f32x4 vzero = {0.f, 0.f, 0.f, 0.f};
  f32x4 st[4];
#pragma unroll
  for (int n = 0; n < 4; ++n) st[n] = vzero;

  for (int j = 0; j < 4; ++j) {
    if (j) __syncthreads();
    {
      // lane = row s within subtile; wave covers d-cols [16w,16w+16)
      const float* krow = k + base + (long)(j * 64 + lane) * D_ + d0;
      const float* vrow = v + base + (long)(j * 64 + lane) * D_ + d0;
      float4 k0 = *(const float4*)(krow + 0),  k1 = *(const float4*)(krow + 4);
      float4 k2 = *(const float4*)(krow + 8),  k3 = *(const float4*)(krow + 12);
      float4 v0 = *(const float4*)(vrow + 0),  v1 = *(const float4*)(vrow + 4);
      float4 v2 = *(const float4*)(vrow + 8),  v3 = *(const float4*)(vrow + 12);
      // bank = (d*36 + lane/2)%32 -> 32 banks, 2 lanes/word: conflict-free
      KT[d0 +  0][lane] = (__bf16)k0.x; KT[d0 +  1][lane] = (__bf16)k0.y;
      KT[d0 +  2][lane] = (__bf16)k0.z; KT[d0 +  3][lane] = (__bf16)k0.w;
      KT[d0 +  4][lane] = (__bf16)k1.x; KT[d0 +  5][lane] = (__bf16)k1.y;
      KT[d0 +  6][lane] = (__bf16)k1.z; KT[d0 +  7][lane] = (__bf16)k1.w;
      KT[d0 +  8][lane] = (__bf16)k2.x; KT[d0 +  9][lane] = (__bf16)k2.y;
      KT[d0 + 10][lane] = (__bf16)k2.z; KT[d0 + 11][lane] = (__bf16)k2.w;
      KT[d0 + 12][lane] = (__bf16)k3.x; KT[d0 + 13][lane] = (__bf16)k3.y;
      KT[d0 + 14][lane] = (__bf16)k3.z; KT[d0 + 15][lane] = (__bf16)k3.w;
      VT[d0 +  0][lane] = (__bf16)v0.x; VT[d0 +  1][lane] = (__bf16)v0.y;
      VT[d0 +  2][lane] = (__bf16)v0.z; VT[d0 +  3][lane] = (__bf16)v0.w;
      VT[d0 +  4][lane] = (__bf16)v1.x; VT[d0 +  5][lane] = (__bf16)v1.y;
      VT[d0 +  6][lane] = (__bf16)v1.z; VT[d0 +  7][lane] = (__bf16)v1.w;
      VT[d0 +  8][lane] = (__bf16)v2.x; VT[d0 +  9][lane] = (__bf16)v2.y;
      VT[d0 + 10][lane] = (__bf16)v2.z; VT[d0 + 11][lane] = (__bf16)v2.w;
      VT[d0 + 12][lane] = (__bf16)v3.x; VT[d0 + 13][lane] = (__bf16)v3.y;
      VT[d0 + 14][lane] = (__bf16)v3.z; VT[d0 + 15][lane] = (__bf16)v3.w;
    }
    __syncthreads();
    // KV[d1][d2] += K^T V; wave w owns d1 rows [16w,16w+16)
    bf16x8 ka0 = *(const bf16x8*)&KT[d0 + l15][quad * 8];
    bf16x8 ka1 = *(const bf16x8*)&KT[d0 + l15][32 + quad * 8];
#pragma unroll
    for (int n = 0; n < 4; ++n) {
      bf16x8 b0 = *(const bf16x8*)&VT[n * 16 + l15][quad * 8];
      bf16x8 b1 = *(const bf16x8*)&VT[n * 16 + l15][32 + quad * 8];
      st[n] = __builtin_amdgcn_mfma_f32_16x16x32_bf16(ka0, b0, st[n], 0, 0, 0);
      st[n] = __builtin_amdgcn_mfma_f32_16x16x32_bf16(ka1, b1, st[n], 0, 0, 0);
    }
  }
  float* wsp = kvws + ((long)blockIdx.x << 12);
#pragma unroll
  for (int n = 0; n < 4; ++n)
#pragma unroll
    for (int rr = 0; rr < 4; ++rr)
      wsp[(d0 + quad * 4 + rr) * 64 + n * 16 + l15] = st[n][rr];
}

// ------------------------- kernel 2: attention ----------------------------
__global__ __launch_bounds__(256, 2) void attn_kernel(
    const float* __restrict__ q, const float* __restrict__ k,
    const float* __restrict__ v, const float* __restrict__ kvws,
    float* __restrict__ out) {
  __shared__ __align__(16) __bf16 Kj[64][LW];      // key subtile [s][d]
  __shared__ __align__(16) __bf16 VT[64][LW];      // val subtile [d][s]
  __shared__ __align__(16) __bf16 KVT[64][LW];     // prefix state [d2][d1]
  __shared__ __align__(16) __bf16 Sw[4][16][LW];   // per-wave S tile [m][s]

  const int tid  = threadIdx.x;
  const int lane = tid & 63;
  const int w    = tid >> 6;
  const int quad = lane >> 4;
  const int l15  = lane & 15;
  const int bh   = blockIdx.x >> 3;
  const int c    = blockIdx.x & (NCH - 1);
  const long base = ((long)bh * T_ + (long)c * CCH) * D_;
  const int d0   = w * 16;

  // Q A-fragments in registers; wave w owns M-tiles {w, w+4, w+8, w+12}
  bf16x8 qf[4][2];
#pragma unroll
  for (int i = 0; i < 4; ++i) {
    const float* qp = q + base + (long)((w + 4 * i) * 16 + l15) * D_ + quad * 8;
#pragma unroll
    for (int ks = 0; ks < 2; ++ks)
      qf[i][ks] = pack8(*(const float4*)(qp + ks * 32),
                        *(const float4*)(qp + ks * 32 + 4));
  }

  // prefix-sum prior chunk states: wave w owns d1 rows [16w,16w+16)
  float kvacc[16];
#pragma unroll
  for (int i = 0; i < 16; ++i) kvacc[i] = 0.f;
  {
    const float* wsbh = kvws + ((long)(bh * NCH) << 12);
    for (int cc = 0; cc < c; ++cc) {
      const float* p = wsbh + ((long)cc << 12) + d0 * 64 + lane;
#pragma unroll
      for (int i = 0; i < 16; ++i) kvacc[i] += p[i * 64];
    }
  }

  // stage subtile j=0 (Kj row-major b128; VT transposed conflict-free)
  {
    const float* krow = k + base + (long)lane * D_ + d0;
    const float* vrow = v + base + (long)lane * D_ + d0;
    float4 k0 = *(const float4*)(krow + 0),  k1 = *(const float4*)(krow + 4);
    float4 k2 = *(const float4*)(krow + 8),  k3 = *(const float4*)(krow + 12);
    float4 v0 = *(const float4*)(vrow + 0),  v1 = *(const float4*)(vrow + 4);
    float4 v2 = *(const float4*)(vrow + 8),  v3 = *(const float4*)(vrow + 12);
    *(bf16x8*)&Kj[lane][d0]     = pack8(k0, k1);
    *(bf16x8*)&Kj[lane][d0 + 8] = pack8(k2, k3);
    VT[d0 +  0][lane] = (__bf16)v0.x; VT[d0 +  1][lane] = (__bf16)v0.y;
    VT[d0 +  2][lane] = (__bf16)v0.z; VT[d0 +  3][lane] = (__bf16)v0.w;
    VT[d0 +  4][lane] = (__bf16)v1.x; VT[d0 +  5][lane] = (__bf16)v1.y;
    VT[d0 +  6][lane] = (__bf16)v1.z; VT[d0 +  7][lane] = (__bf16)v1.w;
    VT[d0 +  8][lane] = (__bf16)v2.x; VT[d0 +  9][lane] = (__bf16)v2.y;
    VT[d0 + 10][lane] = (__bf16)v2.z; VT[d0 + 11][lane] = (__bf16)v2.w;
    VT[d0 + 12][lane] = (__bf16)v3.x; VT[d0 + 13][lane] = (__bf16)v3.y;
    VT[d0 + 14][lane] = (__bf16)v3.z; VT[d0 + 15][lane] = (__bf16)v3.w;
  }
  // KVT[d2=lane][d1=d0+i] packed b128 writes
  {
    float4 a0 = {kvacc[0], kvacc[1], kvacc[2], kvacc[3]};
    float4 a1 = {kvacc[4], kvacc[5], kvacc[6], kvacc[7]};
    float4 a2 = {kvacc[8], kvacc[9], kvacc[10], kvacc[11]};
    float4 a3 = {kvacc[12], kvacc[13], kvacc[14], kvacc[15]};
    *(bf16x8*)&KVT[lane][d0]     = pack8(a0, a1);
    *(bf16x8*)&KVT[lane][d0 + 8] = pack8(a2, a3);
  }

  const f32x4 vzero = {0.f, 0.f, 0.f, 0.f};
  f32x4 acc[4][4];
#pragma unroll
  for (int i = 0; i < 4; ++i)
#pragma unroll
    for (int n = 0; n < 4; ++n) acc[i][n] = vzero;

  __syncthreads();  // Kj(0), VT(0), KVT visible block-wide

  // inter: O += Q @ KVsum  (zeros when c==0)
#pragma unroll
  for (int ks = 0; ks < 2; ++ks)
#pragma unroll
    for (int n = 0; n < 4; ++n) {
      bf16x8 b = *(const bf16x8*)&KVT[n * 16 + l15][ks * 32 + quad * 8];
#pragma unroll
      for (int i = 0; i < 4; ++i)
        acc[i][n] =
            __builtin_amdgcn_mfma_f32_16x16x32_bf16(qf[i][ks], b, acc[i][n], 0, 0, 0);
    }

  // intra causal over 4 key subtiles
  for (int j = 0; j < 4; ++j) {
    if (j) {
      __syncthreads();  // prior subtile reads done
      const float* krow = k + base + (long)(j * 64 + lane) * D_ + d0;
      const float* vrow = v + base + (long)(j * 64 + lane) * D_ + d0;
      float4 k0 = *(const float4*)(krow + 0),  k1 = *(const float4*)(krow + 4);
      float4 k2 = *(const float4*)(krow + 8),  k3 = *(const float4*)(krow + 12);
      float4 v0 = *(const float4*)(vrow + 0),  v1 = *(const float4*)(vrow + 4);
      float4 v2 = *(const float4*)(vrow + 8),  v3 = *(const float4*)(vrow + 12);
      *(bf16x8*)&Kj[lane][d0]     = pack8(k0, k1);
      *(bf16x8*)&Kj[lane][d0 + 8] = pack8(k2, k3);
      VT[d0 +  0][lane] = (__bf16)v0.x; VT[d0 +  1][lane] = (__bf16)v0.y;
      VT[d0 +  2][lane] = (__bf16)v0.z; VT[d0 +  3][lane] = (__bf16)v0.w;
      VT[d0 +  4][lane] = (__bf16)v1.x; VT[d0 +  5][lane] = (__bf16)v1.y;
      VT[d0 +  6][lane] = (__bf16)v1.z; VT[d0 +  7][lane] = (__bf16)v1.w;
      VT[d0 +  8][lane] = (__bf16)v2.x; VT[d0 +  9][lane] = (__bf16)v2.y;
      VT[d0 + 10][lane] = (__bf16)v2.z; VT[d0 + 11][lane] = (__bf16)v2.w;
      VT[d0 + 12][lane] = (__bf16)v3.x; VT[d0 + 13][lane] = (__bf16)v3.y;
      VT[d0 + 14][lane] = (__bf16)v3.z; VT[d0 + 15][lane] = (__bf16)v3.w;
      __syncthreads();  // staging visible
    }

    // cache this subtile's V B-fragments (reused by up to 4 SV gemms)
    bf16x8 vb[2][4];
#pragma unroll
    for (int ks = 0; ks < 2; ++ks)
#pragma unroll
      for (int n = 0; n < 4; ++n)
        vb[ks][n] = *(const bf16x8*)&VT[n * 16 + l15][ks * 32 + quad * 8];

    // M-tile (w+4i) needs subtile j iff i >= j; i==j is the masked diagonal
    for (int i = j; i < 4; ++i) {
      f32x4 s4[4];
#pragma unroll
      for (int n = 0; n < 4; ++n) s4[n] = vzero;
#pragma unroll
      for (int ks = 0; ks < 2; ++ks)
#pragma unroll
        for (int n = 0; n < 4; ++n) {
          bf16x8 b = *(const bf16x8*)&Kj[n * 16 + l15][ks * 32 + quad * 8];
          s4[n] = __builtin_amdgcn_mfma_f32_16x16x32_bf16(qf[i][ks], b, s4[n], 0, 0, 0);
        }
      // mask + C->A round-trip through wave-private Sw (no barriers)
#pragma unroll
      for (int n = 0; n < 4; ++n)
#pragma unroll
        for (int rr = 0; rr < 4; ++rr) {
          float val = s4[n][rr];
          if (i == j && (n * 16 + l15 > 16 * w + quad * 4 + rr)) val = 0.f;
          Sw[w][quad * 4 + rr][n * 16 + l15] = (__bf16)val;
        }
      bf16x8 a0 = *(const bf16x8*)&Sw[w][l15][quad * 8];
      bf16x8 a1 = *(const bf16x8*)&Sw[w][l15][32 + quad * 8];
#pragma unroll
      for (int n = 0; n < 4; ++n) {
        acc[i][n] = __builtin_amdgcn_mfma_f32_16x16x32_bf16(a0, vb[0][n], acc[i][n], 0, 0, 0);
        acc[i][n] = __builtin_amdgcn_mfma_f32_16x16x32_bf16(a1, vb[1][n], acc[i][n], 0, 0, 0);
      }
    }
  }

  // epilogue
  float* op = out + base;
#pragma unroll
  for (int i = 0; i < 4; ++i) {
    int row = (w + 4 * i) * 16 + quad * 4;
#pragma unroll
    for (int n = 0; n < 4; ++n)
#pragma unroll
      for (int rr = 0; rr < 4; ++rr)
        op[(long)(row + rr) * D_ + n * 16 + l15] = acc[i][n][rr];
  }
}

extern "C" void kernel_launch(void* const* d_in, const int* in_sizes, int n_in,
                              void* d_out, int out_size, void* d_ws, size_t ws_size,
                              hipStream_t stream) {
  const float* q = (const float*)d_in[0];
  const float* k = (const float*)d_in[1];
  const float* v = (const float*)d_in[2];
  float* out = (float*)d_out;
  float* kvws = (float*)d_ws;  // 512 * 16 KiB = 8 MiB used

  hipLaunchKernelGGL(state_kernel, dim3(512), dim3(256), 0, stream, k, v, kvws);
  hipLaunchKernelGGL(attn_kernel, dim3(512), dim3(256), 0, stream,
                     q, k, v, kvws, out);
}

// Round 4
// 160.256 us; speedup vs baseline: 1.0160x; 1.0160x over previous
//
#include <hip/hip_runtime.h>
#include <hip/hip_bf16.h>

// Causal linear attention, chunked. B=4 H=16 T=2048 D=64.
// Round 4: C=128, NC=16 -> 1024 blocks/kernel (4 blocks/CU, 16 waves/CU vs
// round-3's 8). Intra FLOPs halve (masked-score work ~ T*C). States stored
// bf16 TRANSPOSED (state^T[d2][d1]) for vectorized prefix reads. KVT shares
// LDS with a double-buffered per-wave Sw (union; KVT dead after inter gemm)
// keeping LDS at 36 KB so the full grid is co-resident.

#define T_   2048
#define D_   64
#define CCH  128
#define NCH  16
#define LW   72   // bf16 row stride 144 B (16B aligned); b128 rows 2-way = free

typedef __bf16 bf16x8 __attribute__((ext_vector_type(8)));
typedef __bf16 bf16x4 __attribute__((ext_vector_type(4)));
typedef __bf16 bf16x2 __attribute__((ext_vector_type(2)));
typedef float  f32x4  __attribute__((ext_vector_type(4)));
typedef unsigned int u32;

// MFMA 16x16x32 bf16 fragment layouts (HW-verified, rounds 1/3 passing):
//   A: A[m = lane&15][k = (lane>>4)*8 + j]
//   B: B[k = (lane>>4)*8 + j][n = lane&15]
//   C/D: row = (lane>>4)*4 + reg, col = lane&15

__device__ inline bf16x8 pack8(float4 a, float4 b) {
  bf16x8 r;
  r[0] = (__bf16)a.x; r[1] = (__bf16)a.y; r[2] = (__bf16)a.z; r[3] = (__bf16)a.w;
  r[4] = (__bf16)b.x; r[5] = (__bf16)b.y; r[6] = (__bf16)b.z; r[7] = (__bf16)b.w;
  return r;
}

// ------------------------- kernel 1: chunk states -------------------------
// state^T[d2][d1] = (K_c^T V_c)^T, bf16, 64x64 row-major per (bh,c).
__global__ __launch_bounds__(256, 4) void state_kernel(
    const float* __restrict__ k, const float* __restrict__ v,
    __bf16* __restrict__ stws) {
  __shared__ __align__(16) __bf16 KT[64][LW];  // [d][s]
  __shared__ __align__(16) __bf16 VT[64][LW];  // [d][s]

  const int tid  = threadIdx.x;
  const int lane = tid & 63;
  const int w    = tid >> 6;
  const int quad = lane >> 4;
  const int l15  = lane & 15;
  const int bh   = (int)blockIdx.x >> 4;
  const int c    = (int)blockIdx.x & (NCH - 1);
  if (c == NCH - 1) return;  // last chunk's state never consumed
  const long base = ((long)bh * T_ + (long)c * CCH) * D_;
  const int d0   = w * 16;

  const f32x4 vzero = {0.f, 0.f, 0.f, 0.f};
  f32x4 st[4];
#pragma unroll
  for (int n = 0; n < 4; ++n) st[n] = vzero;

  for (int j = 0; j < 2; ++j) {  // 2 s-subtiles of 64 cover the 128 chunk
    if (j) __syncthreads();
    {
      const float* krow = k + base + (long)(j * 64 + lane) * D_ + d0;
      const float* vrow = v + base + (long)(j * 64 + lane) * D_ + d0;
      float4 k0 = *(const float4*)(krow + 0),  k1 = *(const float4*)(krow + 4);
      float4 k2 = *(const float4*)(krow + 8),  k3 = *(const float4*)(krow + 12);
      float4 v0 = *(const float4*)(vrow + 0),  v1 = *(const float4*)(vrow + 4);
      float4 v2 = *(const float4*)(vrow + 8),  v3 = *(const float4*)(vrow + 12);
      // bank = (d*36 + lane/2)%32 -> all 32 banks, 2 lanes/word = free
      KT[d0 +  0][lane] = (__bf16)k0.x; KT[d0 +  1][lane] = (__bf16)k0.y;
      KT[d0 +  2][lane] = (__bf16)k0.z; KT[d0 +  3][lane] = (__bf16)k0.w;
      KT[d0 +  4][lane] = (__bf16)k1.x; KT[d0 +  5][lane] = (__bf16)k1.y;
      KT[d0 +  6][lane] = (__bf16)k1.z; KT[d0 +  7][lane] = (__bf16)k1.w;
      KT[d0 +  8][lane] = (__bf16)k2.x; KT[d0 +  9][lane] = (__bf16)k2.y;
      KT[d0 + 10][lane] = (__bf16)k2.z; KT[d0 + 11][lane] = (__bf16)k2.w;
      KT[d0 + 12][lane] = (__bf16)k3.x; KT[d0 + 13][lane] = (__bf16)k3.y;
      KT[d0 + 14][lane] = (__bf16)k3.z; KT[d0 + 15][lane] = (__bf16)k3.w;
      VT[d0 +  0][lane] = (__bf16)v0.x; VT[d0 +  1][lane] = (__bf16)v0.y;
      VT[d0 +  2][lane] = (__bf16)v0.z; VT[d0 +  3][lane] = (__bf16)v0.w;
      VT[d0 +  4][lane] = (__bf16)v1.x; VT[d0 +  5][lane] = (__bf16)v1.y;
      VT[d0 +  6][lane] = (__bf16)v1.z; VT[d0 +  7][lane] = (__bf16)v1.w;
      VT[d0 +  8][lane] = (__bf16)v2.x; VT[d0 +  9][lane] = (__bf16)v2.y;
      VT[d0 + 10][lane] = (__bf16)v2.z; VT[d0 + 11][lane] = (__bf16)v2.w;
      VT[d0 + 12][lane] = (__bf16)v3.x; VT[d0 + 13][lane] = (__bf16)v3.y;
      VT[d0 + 14][lane] = (__bf16)v3.z; VT[d0 + 15][lane] = (__bf16)v3.w;
    }
    __syncthreads();
    // KV[d1][d2] += K^T V; wave w owns d1 rows [16w,16w+16)
    bf16x8 ka0 = *(const bf16x8*)&KT[d0 + l15][quad * 8];
    bf16x8 ka1 = *(const bf16x8*)&KT[d0 + l15][32 + quad * 8];
#pragma unroll
    for (int n = 0; n < 4; ++n) {
      bf16x8 b0 = *(const bf16x8*)&VT[n * 16 + l15][quad * 8];
      bf16x8 b1 = *(const bf16x8*)&VT[n * 16 + l15][32 + quad * 8];
      st[n] = __builtin_amdgcn_mfma_f32_16x16x32_bf16(ka0, b0, st[n], 0, 0, 0);
      st[n] = __builtin_amdgcn_mfma_f32_16x16x32_bf16(ka1, b1, st[n], 0, 0, 0);
    }
  }
  // write TRANSPOSED bf16: stT[d2 = n*16+l15][d1 = d0+quad*4+rr], packed x4
  __bf16* wsp = stws + ((long)blockIdx.x << 12);
#pragma unroll
  for (int n = 0; n < 4; ++n) {
    bf16x4 pk;
    pk[0] = (__bf16)st[n][0]; pk[1] = (__bf16)st[n][1];
    pk[2] = (__bf16)st[n][2]; pk[3] = (__bf16)st[n][3];
    *(bf16x4*)&wsp[(n * 16 + l15) * 64 + d0 + quad * 4] = pk;
  }
}

// ------------------------- kernel 2: attention ----------------------------
__global__ __launch_bounds__(256, 4) void attn_kernel(
    const float* __restrict__ q, const float* __restrict__ k,
    const float* __restrict__ v, const __bf16* __restrict__ stws,
    float* __restrict__ out) {
  __shared__ __align__(16) __bf16 Kj[64][LW];        // key subtile [s][d]
  __shared__ __align__(16) __bf16 VT[64][LW];        // val subtile [d][s]
  // Union region (18432 B): KVT[64][LW] (lives until inter gemm), then
  // per-wave double-buffered Sw[4][2][16][LW].
  __shared__ __align__(16) __bf16 Ubuf[2 * 64 * LW];

  const int tid  = threadIdx.x;
  const int lane = tid & 63;
  const int w    = tid >> 6;
  const int quad = lane >> 4;
  const int l15  = lane & 15;
  const int bh   = (int)blockIdx.x >> 4;
  const int c    = (int)blockIdx.x & (NCH - 1);
  const long base = ((long)bh * T_ + (long)c * CCH) * D_;
  const int d0   = w * 16;

  // Q A-fragments; wave w owns M-tiles {w, w+4} of the 8 in this chunk
  bf16x8 qf[2][2];
#pragma unroll
  for (int i = 0; i < 2; ++i) {
    const float* qp = q + base + (long)((w + 4 * i) * 16 + l15) * D_ + quad * 8;
#pragma unroll
    for (int ks = 0; ks < 2; ++ks)
      qf[i][ks] = pack8(*(const float4*)(qp + ks * 32),
                        *(const float4*)(qp + ks * 32 + 4));
  }

  // stage subtile 0 (Kj row-major b128; VT transposed conflict-free)
  {
    const float* krow = k + base + (long)lane * D_ + d0;
    const float* vrow = v + base + (long)lane * D_ + d0;
    float4 k0 = *(const float4*)(krow + 0),  k1 = *(const float4*)(krow + 4);
    float4 k2 = *(const float4*)(krow + 8),  k3 = *(const float4*)(krow + 12);
    float4 v0 = *(const float4*)(vrow + 0),  v1 = *(const float4*)(vrow + 4);
    float4 v2 = *(const float4*)(vrow + 8),  v3 = *(const float4*)(vrow + 12);
    *(bf16x8*)&Kj[lane][d0]     = pack8(k0, k1);
    *(bf16x8*)&Kj[lane][d0 + 8] = pack8(k2, k3);
    VT[d0 +  0][lane] = (__bf16)v0.x; VT[d0 +  1][lane] = (__bf16)v0.y;
    VT[d0 +  2][lane] = (__bf16)v0.z; VT[d0 +  3][lane] = (__bf16)v0.w;
    VT[d0 +  4][lane] = (__bf16)v1.x; VT[d0 +  5][lane] = (__bf16)v1.y;
    VT[d0 +  6][lane] = (__bf16)v1.z; VT[d0 +  7][lane] = (__bf16)v1.w;
    VT[d0 +  8][lane] = (__bf16)v2.x; VT[d0 +  9][lane] = (__bf16)v2.y;
    VT[d0 + 10][lane] = (__bf16)v2.z; VT[d0 + 11][lane] = (__bf16)v2.w;
    VT[d0 + 12][lane] = (__bf16)v3.x; VT[d0 + 13][lane] = (__bf16)v3.y;
    VT[d0 + 14][lane] = (__bf16)v3.z; VT[d0 + 15][lane] = (__bf16)v3.w;
  }

  // prefix-sum prior states (bf16, transposed): wave w owns d2 rows
  // [16w,16w+16); bf16x2-vectorized: uint idx = w*512 + t*64 + lane
  float2 kv2[8];
#pragma unroll
  for (int t = 0; t < 8; ++t) { kv2[t].x = 0.f; kv2[t].y = 0.f; }
  {
    const u32* wsb = (const u32*)stws + ((long)(bh * NCH) << 11);
    for (int cc = 0; cc < c; ++cc) {
      const u32* p = wsb + ((long)cc << 11) + w * 512 + lane;
#pragma unroll
      for (int t = 0; t < 8; ++t) {
        u32 u = p[t * 64];
        kv2[t].x += __uint_as_float(u << 16);
        kv2[t].y += __uint_as_float(u & 0xffff0000u);
      }
    }
  }
  // KVT[d2 = 16w+2t+(lane>>5)][d1 pair 2*(lane&31)] -- b32 writes, 32 banks
  {
    const int h = lane >> 5, l31 = lane & 31;
#pragma unroll
    for (int t = 0; t < 8; ++t) {
      bf16x2 pr;
      pr[0] = (__bf16)kv2[t].x; pr[1] = (__bf16)kv2[t].y;
      *(bf16x2*)&Ubuf[(16 * w + 2 * t + h) * LW + 2 * l31] = pr;
    }
  }

  const f32x4 vzero = {0.f, 0.f, 0.f, 0.f};
  f32x4 acc[2][4];
#pragma unroll
  for (int i = 0; i < 2; ++i)
#pragma unroll
    for (int n = 0; n < 4; ++n) acc[i][n] = vzero;

  __syncthreads();  // B1: Kj/VT(0), KVT visible

  // inter: O += Q @ KVsum (B[k=d1][n=d2] from KVT[d2][d1]; zeros when c==0)
#pragma unroll
  for (int ks = 0; ks < 2; ++ks)
#pragma unroll
    for (int n = 0; n < 4; ++n) {
      bf16x8 b = *(const bf16x8*)&Ubuf[(n * 16 + l15) * LW + ks * 32 + quad * 8];
      acc[0][n] = __builtin_amdgcn_mfma_f32_16x16x32_bf16(qf[0][ks], b, acc[0][n], 0, 0, 0);
      acc[1][n] = __builtin_amdgcn_mfma_f32_16x16x32_bf16(qf[1][ks], b, acc[1][n], 0, 0, 0);
    }

  // V B-fragments of subtile 0 + both j=0 score tiles (independent streams)
  bf16x8 vb[2][4];
#pragma unroll
  for (int ks = 0; ks < 2; ++ks)
#pragma unroll
    for (int n = 0; n < 4; ++n)
      vb[ks][n] = *(const bf16x8*)&VT[n * 16 + l15][ks * 32 + quad * 8];

  f32x4 sA[4], sB[4];
#pragma unroll
  for (int n = 0; n < 4; ++n) { sA[n] = vzero; sB[n] = vzero; }
#pragma unroll
  for (int ks = 0; ks < 2; ++ks)
#pragma unroll
    for (int n = 0; n < 4; ++n) {
      bf16x8 bK = *(const bf16x8*)&Kj[n * 16 + l15][ks * 32 + quad * 8];
      sA[n] = __builtin_amdgcn_mfma_f32_16x16x32_bf16(qf[0][ks], bK, sA[n], 0, 0, 0);
      sB[n] = __builtin_amdgcn_mfma_f32_16x16x32_bf16(qf[1][ks], bK, sB[n], 0, 0, 0);
    }

  __syncthreads();  // B2: all KVT reads done before Sw overwrites the union

  __bf16* sw0 = &Ubuf[((w * 2 + 0) * 16) * LW];
  __bf16* sw1 = &Ubuf[((w * 2 + 1) * 16) * LW];

  // pair (i=0, j=0): diagonal (M-tile w, keys 0..63) -> mask col > 16w+row
#pragma unroll
  for (int n = 0; n < 4; ++n)
#pragma unroll
    for (int rr = 0; rr < 4; ++rr) {
      float val = sA[n][rr];
      if (n * 16 + l15 > 16 * w + quad * 4 + rr) val = 0.f;
      sw0[(quad * 4 + rr) * LW + n * 16 + l15] = (__bf16)val;
    }
  // pair (i=1, j=0): full tile (M-tile w+4, keys 0..63)
#pragma unroll
  for (int n = 0; n < 4; ++n)
#pragma unroll
    for (int rr = 0; rr < 4; ++rr)
      sw1[(quad * 4 + rr) * LW + n * 16 + l15] = (__bf16)sB[n][rr];

  {
    bf16x8 a0 = *(const bf16x8*)&sw0[l15 * LW + quad * 8];
    bf16x8 a1 = *(const bf16x8*)&sw0[l15 * LW + 32 + quad * 8];
    bf16x8 b0 = *(const bf16x8*)&sw1[l15 * LW + quad * 8];
    bf16x8 b1 = *(const bf16x8*)&sw1[l15 * LW + 32 + quad * 8];
#pragma unroll
    for (int n = 0; n < 4; ++n) {
      acc[0][n] = __builtin_amdgcn_mfma_f32_16x16x32_bf16(a0, vb[0][n], acc[0][n], 0, 0, 0);
      acc[0][n] = __builtin_amdgcn_mfma_f32_16x16x32_bf16(a1, vb[1][n], acc[0][n], 0, 0, 0);
      acc[1][n] = __builtin_amdgcn_mfma_f32_16x16x32_bf16(b0, vb[0][n], acc[1][n], 0, 0, 0);
      acc[1][n] = __builtin_amdgcn_mfma_f32_16x16x32_bf16(b1, vb[1][n], acc[1][n], 0, 0, 0);
    }
  }

  __syncthreads();  // B3: Kj/VT(0) reads drained before restaging

  // stage subtile 1
  {
    const float* krow = k + base + (long)(64 + lane) * D_ + d0;
    const float* vrow = v + base + (long)(64 + lane) * D_ + d0;
    float4 k0 = *(const float4*)(krow + 0),  k1 = *(const float4*)(krow + 4);
    float4 k2 = *(const float4*)(krow + 8),  k3 = *(const float4*)(krow + 12);
    float4 v0 = *(const float4*)(vrow + 0),  v1 = *(const float4*)(vrow + 4);
    float4 v2 = *(const float4*)(vrow + 8),  v3 = *(const float4*)(vrow + 12);
    *(bf16x8*)&Kj[lane][d0]     = pack8(k0, k1);
    *(bf16x8*)&Kj[lane][d0 + 8] = pack8(k2, k3);
    VT[d0 +  0][lane] = (__bf16)v0.x; VT[d0 +  1][lane] = (__bf16)v0.y;
    VT[d0 +  2][lane] = (__bf16)v0.z; VT[d0 +  3][lane] = (__bf16)v0.w;
    VT[d0 +  4][lane] = (__bf16)v1.x; VT[d0 +  5][lane] = (__bf16)v1.y;
    VT[d0 +  6][lane] = (__bf16)v1.z; VT[d0 +  7][lane] = (__bf16)v1.w;
    VT[d0 +  8][lane] = (__bf16)v2.x; VT[d0 +  9][lane] = (__bf16)v2.y;
    VT[d0 + 10][lane] = (__bf16)v2.z; VT[d0 + 11][lane] = (__bf16)v2.w;
    VT[d0 + 12][lane] = (__bf16)v3.x; VT[d0 + 13][lane] = (__bf16)v3.y;
    VT[d0 + 14][lane] = (__bf16)v3.z; VT[d0 + 15][lane] = (__bf16)v3.w;
  }
  __syncthreads();  // B4

  // pair (i=1, j=1): diagonal (M-tile w+4, keys 64..127)
#pragma unroll
  for (int ks = 0; ks < 2; ++ks)
#pragma unroll
    for (int n = 0; n < 4; ++n)
      vb[ks][n] = *(const bf16x8*)&VT[n * 16 + l15][ks * 32 + quad * 8];

  f32x4 sC[4];
#pragma unroll
  for (int n = 0; n < 4; ++n) sC[n] = vzero;
#pragma unroll
  for (int ks = 0; ks < 2; ++ks)
#pragma unroll
    for (int n = 0; n < 4; ++n) {
      bf16x8 bK = *(const bf16x8*)&Kj[n * 16 + l15][ks * 32 + quad * 8];
      sC[n] = __builtin_amdgcn_mfma_f32_16x16x32_bf16(qf[1][ks], bK, sC[n], 0, 0, 0);
    }
#pragma unroll
  for (int n = 0; n < 4; ++n)
#pragma unroll
    for (int rr = 0; rr < 4; ++rr) {
      float val = sC[n][rr];
      if (n * 16 + l15 > 16 * w + quad * 4 + rr) val = 0.f;
      sw0[(quad * 4 + rr) * LW + n * 16 + l15] = (__bf16)val;
    }
  {
    bf16x8 a0 = *(const bf16x8*)&sw0[l15 * LW + quad * 8];
    bf16x8 a1 = *(const bf16x8*)&sw0[l15 * LW + 32 + quad * 8];
#pragma unroll
    for (int n = 0; n < 4; ++n) {
      acc[1][n] = __builtin_amdgcn_mfma_f32_16x16x32_bf16(a0, vb[0][n], acc[1][n], 0, 0, 0);
      acc[1][n] = __builtin_amdgcn_mfma_f32_16x16x32_bf16(a1, vb[1][n], acc[1][n], 0, 0, 0);
    }
  }

  // epilogue
  float* op = out + base;
#pragma unroll
  for (int i = 0; i < 2; ++i) {
    int row = (w + 4 * i) * 16 + quad * 4;
#pragma unroll
    for (int n = 0; n < 4; ++n)
#pragma unroll
      for (int rr = 0; rr < 4; ++rr)
        op[(long)(row + rr) * D_ + n * 16 + l15] = acc[i][n][rr];
  }
}

extern "C" void kernel_launch(void* const* d_in, const int* in_sizes, int n_in,
                              void* d_out, int out_size, void* d_ws, size_t ws_size,
                              hipStream_t stream) {
  const float* q = (const float*)d_in[0];
  const float* k = (const float*)d_in[1];
  const float* v = (const float*)d_in[2];
  float* out = (float*)d_out;
  __bf16* stws = (__bf16*)d_ws;  // 1024 * 4096 bf16 = 8 MiB used

  hipLaunchKernelGGL(state_kernel, dim3(64 * NCH), dim3(256), 0, stream,
                     k, v, stws);
  hipLaunchKernelGGL(attn_kernel, dim3(64 * NCH), dim3(256), 0, stream,
                     q, k, v, stws, out);
}

// Round 5
// 158.330 us; speedup vs baseline: 1.0284x; 1.0122x over previous
//
#include <hip/hip_runtime.h>
#include <hip/hip_bf16.h>

// Causal linear attention, chunked. B=4 H=16 T=2048 D=64. C=128, NC=16.
// Round 5: three dispatches.
//  1) state_kernel: per-(bh,c) chunk state  S_c^T = (K_c^T V_c)^T  bf16 -> ws
//  2) scan_kernel:  cumulative states cum[c] = sum_{cc<=c} S_cc  (8 MB scan)
//  3) attn_kernel:  O = Q_c @ cum[c-1] + tril(Q_c K_c^T) @ V_c
// attn blocks are now UNIFORM (1 state read each, no quadratic prefix loop,
// no load imbalance) and the state B-fragments are loaded DIRECTLY from
// global (transposed layout makes each fragment one contiguous dwordx4).

#define T_   2048
#define D_   64
#define CCH  128
#define NCH  16
#define LW   72   // bf16 row stride 144 B (16B aligned)

typedef __bf16 bf16x8 __attribute__((ext_vector_type(8)));
typedef __bf16 bf16x4 __attribute__((ext_vector_type(4)));
typedef float  f32x4  __attribute__((ext_vector_type(4)));

// MFMA 16x16x32 bf16 fragment layouts (HW-verified, rounds 1/3/4 passing):
//   A: A[m = lane&15][k = (lane>>4)*8 + j]
//   B: B[k = (lane>>4)*8 + j][n = lane&15]
//   C/D: row = (lane>>4)*4 + reg, col = lane&15

__device__ inline bf16x8 pack8(float4 a, float4 b) {
  bf16x8 r;
  r[0] = (__bf16)a.x; r[1] = (__bf16)a.y; r[2] = (__bf16)a.z; r[3] = (__bf16)a.w;
  r[4] = (__bf16)b.x; r[5] = (__bf16)b.y; r[6] = (__bf16)b.z; r[7] = (__bf16)b.w;
  return r;
}

// ------------------------- kernel 1: chunk states -------------------------
// state^T[d2][d1] = (K_c^T V_c)^T, bf16, 64x64 row-major per (bh,c).
__global__ __launch_bounds__(256, 4) void state_kernel(
    const float* __restrict__ k, const float* __restrict__ v,
    __bf16* __restrict__ stws) {
  __shared__ __align__(16) __bf16 KT[64][LW];  // [d][s]
  __shared__ __align__(16) __bf16 VT[64][LW];  // [d][s]

  const int tid  = threadIdx.x;
  const int lane = tid & 63;
  const int w    = tid >> 6;
  const int quad = lane >> 4;
  const int l15  = lane & 15;
  const int bh   = (int)blockIdx.x >> 4;
  const int c    = (int)blockIdx.x & (NCH - 1);
  if (c == NCH - 1) return;  // last chunk's state never consumed
  const long base = ((long)bh * T_ + (long)c * CCH) * D_;
  const int d0   = w * 16;

  const f32x4 vzero = {0.f, 0.f, 0.f, 0.f};
  f32x4 st[4];
#pragma unroll
  for (int n = 0; n < 4; ++n) st[n] = vzero;

  for (int j = 0; j < 2; ++j) {
    if (j) __syncthreads();
    {
      const float* krow = k + base + (long)(j * 64 + lane) * D_ + d0;
      const float* vrow = v + base + (long)(j * 64 + lane) * D_ + d0;
      float4 k0 = *(const float4*)(krow + 0),  k1 = *(const float4*)(krow + 4);
      float4 k2 = *(const float4*)(krow + 8),  k3 = *(const float4*)(krow + 12);
      float4 v0 = *(const float4*)(vrow + 0),  v1 = *(const float4*)(vrow + 4);
      float4 v2 = *(const float4*)(vrow + 8),  v3 = *(const float4*)(vrow + 12);
      // bank = (d*36 + lane/2)%32 -> all 32 banks, 2 lanes/word = free
      KT[d0 +  0][lane] = (__bf16)k0.x; KT[d0 +  1][lane] = (__bf16)k0.y;
      KT[d0 +  2][lane] = (__bf16)k0.z; KT[d0 +  3][lane] = (__bf16)k0.w;
      KT[d0 +  4][lane] = (__bf16)k1.x; KT[d0 +  5][lane] = (__bf16)k1.y;
      KT[d0 +  6][lane] = (__bf16)k1.z; KT[d0 +  7][lane] = (__bf16)k1.w;
      KT[d0 +  8][lane] = (__bf16)k2.x; KT[d0 +  9][lane] = (__bf16)k2.y;
      KT[d0 + 10][lane] = (__bf16)k2.z; KT[d0 + 11][lane] = (__bf16)k2.w;
      KT[d0 + 12][lane] = (__bf16)k3.x; KT[d0 + 13][lane] = (__bf16)k3.y;
      KT[d0 + 14][lane] = (__bf16)k3.z; KT[d0 + 15][lane] = (__bf16)k3.w;
      VT[d0 +  0][lane] = (__bf16)v0.x; VT[d0 +  1][lane] = (__bf16)v0.y;
      VT[d0 +  2][lane] = (__bf16)v0.z; VT[d0 +  3][lane] = (__bf16)v0.w;
      VT[d0 +  4][lane] = (__bf16)v1.x; VT[d0 +  5][lane] = (__bf16)v1.y;
      VT[d0 +  6][lane] = (__bf16)v1.z; VT[d0 +  7][lane] = (__bf16)v1.w;
      VT[d0 +  8][lane] = (__bf16)v2.x; VT[d0 +  9][lane] = (__bf16)v2.y;
      VT[d0 + 10][lane] = (__bf16)v2.z; VT[d0 + 11][lane] = (__bf16)v2.w;
      VT[d0 + 12][lane] = (__bf16)v3.x; VT[d0 + 13][lane] = (__bf16)v3.y;
      VT[d0 + 14][lane] = (__bf16)v3.z; VT[d0 + 15][lane] = (__bf16)v3.w;
    }
    __syncthreads();
    // KV[d1][d2] += K^T V; wave w owns d1 rows [16w,16w+16)
    bf16x8 ka0 = *(const bf16x8*)&KT[d0 + l15][quad * 8];
    bf16x8 ka1 = *(const bf16x8*)&KT[d0 + l15][32 + quad * 8];
#pragma unroll
    for (int n = 0; n < 4; ++n) {
      bf16x8 b0 = *(const bf16x8*)&VT[n * 16 + l15][quad * 8];
      bf16x8 b1 = *(const bf16x8*)&VT[n * 16 + l15][32 + quad * 8];
      st[n] = __builtin_amdgcn_mfma_f32_16x16x32_bf16(ka0, b0, st[n], 0, 0, 0);
      st[n] = __builtin_amdgcn_mfma_f32_16x16x32_bf16(ka1, b1, st[n], 0, 0, 0);
    }
  }
  // write TRANSPOSED bf16: stT[d2 = n*16+l15][d1 = d0+quad*4+rr], packed x4
  __bf16* wsp = stws + ((long)blockIdx.x << 12);
#pragma unroll
  for (int n = 0; n < 4; ++n) {
    bf16x4 pk;
    pk[0] = (__bf16)st[n][0]; pk[1] = (__bf16)st[n][1];
    pk[2] = (__bf16)st[n][2]; pk[3] = (__bf16)st[n][3];
    *(bf16x4*)&wsp[(n * 16 + l15) * 64 + d0 + quad * 4] = pk;
  }
}

// ------------------------- kernel 2: cumulative scan ----------------------
// cum[bh][c] = sum_{cc<=c} state[bh][cc], c = 0..NCH-2. Elementwise; layout
// preserved. 512 blocks x 64 threads; each block owns a 1 KB slice and
// scans 15 chunks with a 2-stage software pipeline (loads independent).
__global__ __launch_bounds__(64) void scan_kernel(
    const __bf16* __restrict__ st, __bf16* __restrict__ cum) {
  const int t  = threadIdx.x;
  const int bh = (int)blockIdx.x >> 3;
  const int sl = (int)blockIdx.x & 7;
  const long sbase = ((long)bh * NCH) << 12;   // bf16 elements per bh-group
  const int off = sl * 512 + t * 8;            // 8 bf16 = 16 B per thread

  float acc[8];
#pragma unroll
  for (int i = 0; i < 8; ++i) acc[i] = 0.f;

  bf16x8 cur = *(const bf16x8*)(st + sbase + off);  // chunk 0
  for (int c = 0; c < NCH - 1; ++c) {
    bf16x8 nxt;
    if (c + 1 < NCH - 1)
      nxt = *(const bf16x8*)(st + sbase + ((long)(c + 1) << 12) + off);
#pragma unroll
    for (int i = 0; i < 8; ++i) acc[i] += (float)cur[i];
    bf16x8 o;
#pragma unroll
    for (int i = 0; i < 8; ++i) o[i] = (__bf16)acc[i];
    *(bf16x8*)(cum + sbase + ((long)c << 12) + off) = o;
    cur = nxt;
  }
}

// ------------------------- kernel 3: attention ----------------------------
__global__ __launch_bounds__(256, 4) void attn_kernel(
    const float* __restrict__ q, const float* __restrict__ k,
    const float* __restrict__ v, const __bf16* __restrict__ cum,
    float* __restrict__ out) {
  __shared__ __align__(16) __bf16 Kj[64][LW];        // key subtile [s][d]
  __shared__ __align__(16) __bf16 VT[64][LW];        // val subtile [d][s]
  __shared__ __align__(16) __bf16 Sw[4][2][16][LW];  // per-wave S, dbuf

  const int tid  = threadIdx.x;
  const int lane = tid & 63;
  const int w    = tid >> 6;
  const int quad = lane >> 4;
  const int l15  = lane & 15;
  const int bh   = (int)blockIdx.x >> 4;
  const int c    = (int)blockIdx.x & (NCH - 1);
  const long base = ((long)bh * T_ + (long)c * CCH) * D_;
  const int d0   = w * 16;

  // stage subtile 0 (Kj row-major b128; VT transposed conflict-free)
  {
    const float* krow = k + base + (long)lane * D_ + d0;
    const float* vrow = v + base + (long)lane * D_ + d0;
    float4 k0 = *(const float4*)(krow + 0),  k1 = *(const float4*)(krow + 4);
    float4 k2 = *(const float4*)(krow + 8),  k3 = *(const float4*)(krow + 12);
    float4 v0 = *(const float4*)(vrow + 0),  v1 = *(const float4*)(vrow + 4);
    float4 v2 = *(const float4*)(vrow + 8),  v3 = *(const float4*)(vrow + 12);
    *(bf16x8*)&Kj[lane][d0]     = pack8(k0, k1);
    *(bf16x8*)&Kj[lane][d0 + 8] = pack8(k2, k3);
    VT[d0 +  0][lane] = (__bf16)v0.x; VT[d0 +  1][lane] = (__bf16)v0.y;
    VT[d0 +  2][lane] = (__bf16)v0.z; VT[d0 +  3][lane] = (__bf16)v0.w;
    VT[d0 +  4][lane] = (__bf16)v1.x; VT[d0 +  5][lane] = (__bf16)v1.y;
    VT[d0 +  6][lane] = (__bf16)v1.z; VT[d0 +  7][lane] = (__bf16)v1.w;
    VT[d0 +  8][lane] = (__bf16)v2.x; VT[d0 +  9][lane] = (__bf16)v2.y;
    VT[d0 + 10][lane] = (__bf16)v2.z; VT[d0 + 11][lane] = (__bf16)v2.w;
    VT[d0 + 12][lane] = (__bf16)v3.x; VT[d0 + 13][lane] = (__bf16)v3.y;
    VT[d0 + 14][lane] = (__bf16)v3.z; VT[d0 + 15][lane] = (__bf16)v3.w;
  }

  // Q A-fragments; wave w owns M-tiles {w, w+4} of the 8 in this chunk
  bf16x8 qf[2][2];
#pragma unroll
  for (int i = 0; i < 2; ++i) {
    const float* qp = q + base + (long)((w + 4 * i) * 16 + l15) * D_ + quad * 8;
#pragma unroll
    for (int ks = 0; ks < 2; ++ks)
      qf[i][ks] = pack8(*(const float4*)(qp + ks * 32),
                        *(const float4*)(qp + ks * 32 + 4));
  }

  // cumulative-state B-fragments, DIRECT from global (16 B contiguous each):
  // B[k=d1][n=d2] = cumT[d2][d1]; lane reads cumT row n*16+l15, 8 d1's.
  bf16x8 kvf[2][4];
  if (c) {
    const __bf16* cp = cum + ((long)(bh * NCH + (c - 1)) << 12);
#pragma unroll
    for (int ks = 0; ks < 2; ++ks)
#pragma unroll
      for (int n = 0; n < 4; ++n)
        kvf[ks][n] =
            *(const bf16x8*)(cp + (n * 16 + l15) * 64 + ks * 32 + quad * 8);
  }

  const f32x4 vzero = {0.f, 0.f, 0.f, 0.f};
  f32x4 acc[2][4];
#pragma unroll
  for (int i = 0; i < 2; ++i)
#pragma unroll
    for (int n = 0; n < 4; ++n) acc[i][n] = vzero;

  __syncthreads();  // B1: Kj/VT(0) visible

  // inter: O += Q @ cum[c-1]  (skipped for c==0; block-uniform branch)
  if (c) {
#pragma unroll
    for (int ks = 0; ks < 2; ++ks)
#pragma unroll
      for (int n = 0; n < 4; ++n) {
        acc[0][n] = __builtin_amdgcn_mfma_f32_16x16x32_bf16(qf[0][ks], kvf[ks][n], acc[0][n], 0, 0, 0);
        acc[1][n] = __builtin_amdgcn_mfma_f32_16x16x32_bf16(qf[1][ks], kvf[ks][n], acc[1][n], 0, 0, 0);
      }
  }

  // V B-fragments of subtile 0 + both j=0 score tiles (independent streams)
  bf16x8 vb[2][4];
#pragma unroll
  for (int ks = 0; ks < 2; ++ks)
#pragma unroll
    for (int n = 0; n < 4; ++n)
      vb[ks][n] = *(const bf16x8*)&VT[n * 16 + l15][ks * 32 + quad * 8];

  f32x4 sA[4], sB[4];
#pragma unroll
  for (int n = 0; n < 4; ++n) { sA[n] = vzero; sB[n] = vzero; }
#pragma unroll
  for (int ks = 0; ks < 2; ++ks)
#pragma unroll
    for (int n = 0; n < 4; ++n) {
      bf16x8 bK = *(const bf16x8*)&Kj[n * 16 + l15][ks * 32 + quad * 8];
      sA[n] = __builtin_amdgcn_mfma_f32_16x16x32_bf16(qf[0][ks], bK, sA[n], 0, 0, 0);
      sB[n] = __builtin_amdgcn_mfma_f32_16x16x32_bf16(qf[1][ks], bK, sB[n], 0, 0, 0);
    }

  __bf16* sw0 = &Sw[w][0][0][0];
  __bf16* sw1 = &Sw[w][1][0][0];

  // pair (i=0, j=0): diagonal (M-tile w, keys 0..63) -> mask col > 16w+row
#pragma unroll
  for (int n = 0; n < 4; ++n)
#pragma unroll
    for (int rr = 0; rr < 4; ++rr) {
      float val = sA[n][rr];
      if (n * 16 + l15 > 16 * w + quad * 4 + rr) val = 0.f;
      sw0[(quad * 4 + rr) * LW + n * 16 + l15] = (__bf16)val;
    }
  // pair (i=1, j=0): full tile (M-tile w+4, keys 0..63)
#pragma unroll
  for (int n = 0; n < 4; ++n)
#pragma unroll
    for (int rr = 0; rr < 4; ++rr)
      sw1[(quad * 4 + rr) * LW + n * 16 + l15] = (__bf16)sB[n][rr];

  {
    bf16x8 a0 = *(const bf16x8*)&sw0[l15 * LW + quad * 8];
    bf16x8 a1 = *(const bf16x8*)&sw0[l15 * LW + 32 + quad * 8];
    bf16x8 b0 = *(const bf16x8*)&sw1[l15 * LW + quad * 8];
    bf16x8 b1 = *(const bf16x8*)&sw1[l15 * LW + 32 + quad * 8];
#pragma unroll
    for (int n = 0; n < 4; ++n) {
      acc[0][n] = __builtin_amdgcn_mfma_f32_16x16x32_bf16(a0, vb[0][n], acc[0][n], 0, 0, 0);
      acc[0][n] = __builtin_amdgcn_mfma_f32_16x16x32_bf16(a1, vb[1][n], acc[0][n], 0, 0, 0);
      acc[1][n] = __builtin_amdgcn_mfma_f32_16x16x32_bf16(b0, vb[0][n], acc[1][n], 0, 0, 0);
      acc[1][n] = __builtin_amdgcn_mfma_f32_16x16x32_bf16(b1, vb[1][n], acc[1][n], 0, 0, 0);
    }
  }

  __syncthreads();  // B2: Kj/VT(0) reads drained before restaging

  // stage subtile 1
  {
    const float* krow = k + base + (long)(64 + lane) * D_ + d0;
    const float* vrow = v + base + (long)(64 + lane) * D_ + d0;
    float4 k0 = *(const float4*)(krow + 0),  k1 = *(const float4*)(krow + 4);
    float4 k2 = *(const float4*)(krow + 8),  k3 = *(const float4*)(krow + 12);
    float4 v0 = *(const float4*)(vrow + 0),  v1 = *(const float4*)(vrow + 4);
    float4 v2 = *(const float4*)(vrow + 8),  v3 = *(const float4*)(vrow + 12);
    *(bf16x8*)&Kj[lane][d0]     = pack8(k0, k1);
    *(bf16x8*)&Kj[lane][d0 + 8] = pack8(k2, k3);
    VT[d0 +  0][lane] = (__bf16)v0.x; VT[d0 +  1][lane] = (__bf16)v0.y;
    VT[d0 +  2][lane] = (__bf16)v0.z; VT[d0 +  3][lane] = (__bf16)v0.w;
    VT[d0 +  4][lane] = (__bf16)v1.x; VT[d0 +  5][lane] = (__bf16)v1.y;
    VT[d0 +  6][lane] = (__bf16)v1.z; VT[d0 +  7][lane] = (__bf16)v1.w;
    VT[d0 +  8][lane] = (__bf16)v2.x; VT[d0 +  9][lane] = (__bf16)v2.y;
    VT[d0 + 10][lane] = (__bf16)v2.z; VT[d0 + 11][lane] = (__bf16)v2.w;
    VT[d0 + 12][lane] = (__bf16)v3.x; VT[d0 + 13][lane] = (__bf16)v3.y;
    VT[d0 + 14][lane] = (__bf16)v3.z; VT[d0 + 15][lane] = (__bf16)v3.w;
  }
  __syncthreads();  // B3: subtile 1 visible

  // pair (i=1, j=1): diagonal (M-tile w+4, keys 64..127)
#pragma unroll
  for (int ks = 0; ks < 2; ++ks)
#pragma unroll
    for (int n = 0; n < 4; ++n)
      vb[ks][n] = *(const bf16x8*)&VT[n * 16 + l15][ks * 32 + quad * 8];

  f32x4 sC[4];
#pragma unroll
  for (int n = 0; n < 4; ++n) sC[n] = vzero;
#pragma unroll
  for (int ks = 0; ks < 2; ++ks)
#pragma unroll
    for (int n = 0; n < 4; ++n) {
      bf16x8 bK = *(const bf16x8*)&Kj[n * 16 + l15][ks * 32 + quad * 8];
      sC[n] = __builtin_amdgcn_mfma_f32_16x16x32_bf16(qf[1][ks], bK, sC[n], 0, 0, 0);
    }
#pragma unroll
  for (int n = 0; n < 4; ++n)
#pragma unroll
    for (int rr = 0; rr < 4; ++rr) {
      float val = sC[n][rr];
      if (n * 16 + l15 > 16 * w + quad * 4 + rr) val = 0.f;
      sw0[(quad * 4 + rr) * LW + n * 16 + l15] = (__bf16)val;
    }
  {
    bf16x8 a0 = *(const bf16x8*)&sw0[l15 * LW + quad * 8];
    bf16x8 a1 = *(const bf16x8*)&sw0[l15 * LW + 32 + quad * 8];
#pragma unroll
    for (int n = 0; n < 4; ++n) {
      acc[1][n] = __builtin_amdgcn_mfma_f32_16x16x32_bf16(a0, vb[0][n], acc[1][n], 0, 0, 0);
      acc[1][n] = __builtin_amdgcn_mfma_f32_16x16x32_bf16(a1, vb[1][n], acc[1][n], 0, 0, 0);
    }
  }

  // epilogue
  float* op = out + base;
#pragma unroll
  for (int i = 0; i < 2; ++i) {
    int row = (w + 4 * i) * 16 + quad * 4;
#pragma unroll
    for (int n = 0; n < 4; ++n)
#pragma unroll
      for (int rr = 0; rr < 4; ++rr)
        op[(long)(row + rr) * D_ + n * 16 + l15] = acc[i][n][rr];
  }
}

extern "C" void kernel_launch(void* const* d_in, const int* in_sizes, int n_in,
                              void* d_out, int out_size, void* d_ws, size_t ws_size,
                              hipStream_t stream) {
  const float* q = (const float*)d_in[0];
  const float* k = (const float*)d_in[1];
  const float* v = (const float*)d_in[2];
  float* out = (float*)d_out;
  __bf16* stws = (__bf16*)d_ws;                    // per-chunk states, 8 MiB
  __bf16* cum  = stws + ((long)64 * NCH << 12);    // cumulative states, 8 MiB

  hipLaunchKernelGGL(state_kernel, dim3(64 * NCH), dim3(256), 0, stream,
                     k, v, stws);
  hipLaunchKernelGGL(scan_kernel, dim3(64 * 8), dim3(64), 0, stream,
                     stws, cum);
  hipLaunchKernelGGL(attn_kernel, dim3(64 * NCH), dim3(256), 0, stream,
                     q, k, v, cum, out);
}